// Round 2
// baseline (4420.429 us; speedup 1.0000x reference)
//
#include <hip/hip_runtime.h>
#include <hip/hip_bf16.h>

#define NORM_EPS_F 1e-6f
#define COS_EPS_F  1e-8f
#define BK   1024      // vertices per bucket
#define BKSH 10

__device__ __forceinline__ void atomAddF(float* p, float v) {
    unsafeAtomicAdd(p, v);   // hardware global_atomic_add_f32
}

// ======================= FAST PATH (bucketed, no global fp32 atomics) =======================

// Repack V (N x 3 floats) into float4 for aligned 16B gathers.
__global__ void __launch_bounds__(256) pack_verts_kernel(
    const float* __restrict__ Vr, const float* __restrict__ Vg,
    float4* __restrict__ Vr4, float4* __restrict__ Vg4, int N)
{
    int i = blockIdx.x * blockDim.x + threadIdx.x;
    if (i >= N) return;
    Vr4[i] = make_float4(Vr[3 * i], Vr[3 * i + 1], Vr[3 * i + 2], 0.f);
    Vg4[i] = make_float4(Vg[3 * i], Vg[3 * i + 1], Vg[3 * i + 2], 0.f);
}

// Face normals for both meshes -> global float4 arrays (coalesced writes, no atomics).
__global__ void __launch_bounds__(256) face_normals2_kernel(
    const float4* __restrict__ Vr4, const float4* __restrict__ Vg4,
    const int* __restrict__ faces,
    float4* __restrict__ fnr, float4* __restrict__ fng, int F)
{
    int f = blockIdx.x * blockDim.x + threadIdx.x;
    if (f >= F) return;
    int i0 = faces[3 * f], i1 = faces[3 * f + 1], i2 = faces[3 * f + 2];
    {
        float4 v0 = Vr4[i0], v1 = Vr4[i1], v2 = Vr4[i2];
        float ax = v1.x - v0.x, ay = v1.y - v0.y, az = v1.z - v0.z;
        float bx = v2.x - v0.x, by = v2.y - v0.y, bz = v2.z - v0.z;
        fnr[f] = make_float4(ay * bz - az * by, az * bx - ax * bz, ax * by - ay * bx, 0.f);
    }
    {
        float4 v0 = Vg4[i0], v1 = Vg4[i1], v2 = Vg4[i2];
        float ax = v1.x - v0.x, ay = v1.y - v0.y, az = v1.z - v0.z;
        float bx = v2.x - v0.x, by = v2.y - v0.y, bz = v2.z - v0.z;
        fng[f] = make_float4(ay * bz - az * by, az * bx - ax * bz, ax * by - ay * bx, 0.f);
    }
}

// Bucket face incidences (vertex, face) by vertex>>10.
// Per block: LDS histogram -> one global int atomic per touched bucket -> scatter records.
__global__ void __launch_bounds__(256) bucket_faces_kernel(
    const int* __restrict__ faces, int* __restrict__ cntF,
    int2* __restrict__ recF, int capF, int F, int NB, int chunk)
{
    __shared__ int hist[1024];
    int f0 = blockIdx.x * chunk;
    int f1 = min(f0 + chunk, F);
    for (int b = threadIdx.x; b < NB; b += blockDim.x) hist[b] = 0;
    __syncthreads();
    for (int f = f0 + threadIdx.x; f < f1; f += blockDim.x) {
        atomicAdd(&hist[faces[3 * f] >> BKSH], 1);
        atomicAdd(&hist[faces[3 * f + 1] >> BKSH], 1);
        atomicAdd(&hist[faces[3 * f + 2] >> BKSH], 1);
    }
    __syncthreads();
    for (int b = threadIdx.x; b < NB; b += blockDim.x) {
        int h = hist[b];
        if (h) hist[b] = atomicAdd(&cntF[b], h);   // reserve [base, base+h)
    }
    __syncthreads();
    for (int f = f0 + threadIdx.x; f < f1; f += blockDim.x) {
        int vv0 = faces[3 * f], vv1 = faces[3 * f + 1], vv2 = faces[3 * f + 2];
        int v[3] = {vv0, vv1, vv2};
        #pragma unroll
        for (int c = 0; c < 3; ++c) {
            int b = v[c] >> BKSH;
            int pos = atomicAdd(&hist[b], 1);      // LDS cursor from reserved base
            if (pos < capF)
                recF[(size_t)b * capF + pos] = make_int2(v[c] & (BK - 1), f);
        }
    }
}

// Bucket Laplacian triplets (row, col, val) by row>>10. Same two-phase scheme.
__global__ void __launch_bounds__(256) bucket_L_kernel(
    const int* __restrict__ rows, const int* __restrict__ cols,
    const float* __restrict__ vals, int* __restrict__ cntL,
    int4* __restrict__ recL, int capL, int nnz, int NB, int chunk)
{
    __shared__ int hist[1024];
    int i0 = blockIdx.x * chunk;
    int i1 = min(i0 + chunk, nnz);
    for (int b = threadIdx.x; b < NB; b += blockDim.x) hist[b] = 0;
    __syncthreads();
    for (int i = i0 + threadIdx.x; i < i1; i += blockDim.x)
        atomicAdd(&hist[rows[i] >> BKSH], 1);
    __syncthreads();
    for (int b = threadIdx.x; b < NB; b += blockDim.x) {
        int h = hist[b];
        if (h) hist[b] = atomicAdd(&cntL[b], h);
    }
    __syncthreads();
    for (int i = i0 + threadIdx.x; i < i1; i += blockDim.x) {
        int r = rows[i];
        int b = r >> BKSH;
        int pos = atomicAdd(&hist[b], 1);
        if (pos < capL)
            recL[(size_t)b * capL + pos] =
                make_int4(r & (BK - 1), cols[i], __float_as_int(vals[i]), 0);
    }
}

// One block per bucket: accumulate vertex normals + laplacians in LDS,
// then compute all three loss terms for the bucket's vertices; 4 global atomics/block.
__global__ void __launch_bounds__(256) accum_loss_kernel(
    const float4* __restrict__ Vr4, const float4* __restrict__ Vg4,
    const float4* __restrict__ fnr, const float4* __restrict__ fng,
    const int* __restrict__ cntF, const int2* __restrict__ recF, int capF,
    const int* __restrict__ cntL, const int4* __restrict__ recL, int capL,
    float* __restrict__ accum, int N)
{
    __shared__ float sm[12 * BK];          // 48 KB: vnr, vng, dlr, dlg (3*BK each)
    float* vnr = sm;
    float* vng = sm + 3 * BK;
    float* dlr = sm + 6 * BK;
    float* dlg = sm + 9 * BK;
    int b = blockIdx.x;
    for (int i = threadIdx.x; i < 12 * BK; i += blockDim.x) sm[i] = 0.f;
    __syncthreads();

    int nF = min(cntF[b], capF);
    for (int i = threadIdx.x; i < nF; i += blockDim.x) {
        int2 r = recF[(size_t)b * capF + i];
        float4 a = fnr[r.y];
        float4 c = fng[r.y];
        atomicAdd(&vnr[3 * r.x + 0], a.x);
        atomicAdd(&vnr[3 * r.x + 1], a.y);
        atomicAdd(&vnr[3 * r.x + 2], a.z);
        atomicAdd(&vng[3 * r.x + 0], c.x);
        atomicAdd(&vng[3 * r.x + 1], c.y);
        atomicAdd(&vng[3 * r.x + 2], c.z);
    }
    int nL = min(cntL[b], capL);
    for (int i = threadIdx.x; i < nL; i += blockDim.x) {
        int4 r = recL[(size_t)b * capL + i];
        float v = __int_as_float(r.z);
        float4 pr = Vr4[r.y];
        float4 pg = Vg4[r.y];
        atomicAdd(&dlr[3 * r.x + 0], v * pr.x);
        atomicAdd(&dlr[3 * r.x + 1], v * pr.y);
        atomicAdd(&dlr[3 * r.x + 2], v * pr.z);
        atomicAdd(&dlg[3 * r.x + 0], v * pg.x);
        atomicAdd(&dlg[3 * r.x + 1], v * pg.y);
        atomicAdd(&dlg[3 * r.x + 2], v * pg.z);
    }
    __syncthreads();

    float l1 = 0.f, ln = 0.f, ll = 0.f, nonfin = 0.f;
    for (int lv = threadIdx.x; lv < BK; lv += blockDim.x) {
        int gv = (b << BKSH) + lv;
        if (gv >= N) break;
        float4 r4 = Vr4[gv], g4 = Vg4[gv];
        l1 += fabsf(r4.x - g4.x) + fabsf(r4.y - g4.y) + fabsf(r4.z - g4.z);

        // normal cosine — same numerics as reference (normalize, then cos)
        float ax = vnr[3 * lv], ay = vnr[3 * lv + 1], az = vnr[3 * lv + 2];
        float bx = vng[3 * lv], by = vng[3 * lv + 1], bz = vng[3 * lv + 2];
        float na = sqrtf(ax * ax + ay * ay + az * az);
        float nb = sqrtf(bx * bx + by * by + bz * bz);
        float ia = 1.0f / fmaxf(na, NORM_EPS_F);
        float ib = 1.0f / fmaxf(nb, NORM_EPS_F);
        ax *= ia; ay *= ia; az *= ia;
        bx *= ib; by *= ib; bz *= ib;
        float dot = ax * bx + ay * by + az * bz;
        float nna = sqrtf(ax * ax + ay * ay + az * az);
        float nnb = sqrtf(bx * bx + by * by + bz * bz);
        float cosn = dot / (fmaxf(nna, COS_EPS_F) * fmaxf(nnb, COS_EPS_F));
        if (isnan(cosn)) cosn = 1.0f;
        ln += 1.0f - cosn;

        // laplacian cosine
        float px = dlr[3 * lv], py = dlr[3 * lv + 1], pz = dlr[3 * lv + 2];
        float qx = dlg[3 * lv], qy = dlg[3 * lv + 1], qz = dlg[3 * lv + 2];
        bool fin = isfinite(px) && isfinite(py) && isfinite(pz) &&
                   isfinite(qx) && isfinite(qy) && isfinite(qz);
        nonfin += fin ? 0.f : 1.f;
        float dotl = px * qx + py * qy + pz * qz;
        float npn = sqrtf(px * px + py * py + pz * pz);
        float nqn = sqrtf(qx * qx + qy * qy + qz * qz);
        float cosl = dotl / (fmaxf(npn, COS_EPS_F) * fmaxf(nqn, COS_EPS_F));
        if (isnan(cosl)) cosl = 1.0f;
        ll += 1.0f - cosl;
    }

    for (int off = 32; off > 0; off >>= 1) {
        l1     += __shfl_down(l1, off, 64);
        ln     += __shfl_down(ln, off, 64);
        ll     += __shfl_down(ll, off, 64);
        nonfin += __shfl_down(nonfin, off, 64);
    }
    __shared__ float red[4][4];
    int wave = threadIdx.x >> 6, lane = threadIdx.x & 63;
    if (lane == 0) { red[wave][0] = l1; red[wave][1] = ln; red[wave][2] = ll; red[wave][3] = nonfin; }
    __syncthreads();
    if (threadIdx.x == 0) {
        float a = 0, bb = 0, c = 0, d = 0;
        for (int w = 0; w < 4; ++w) { a += red[w][0]; bb += red[w][1]; c += red[w][2]; d += red[w][3]; }
        atomAddF(&accum[0], a); atomAddF(&accum[1], bb);
        atomAddF(&accum[2], c); atomAddF(&accum[3], d);
    }
}

__global__ void finalize_kernel(const float* __restrict__ accum,
                                float* __restrict__ out, int N)
{
    float invN = 1.0f / (float)N;
    float l1 = accum[0] * invN * (1.0f / 3.0f);
    float ln = accum[1] * invN;
    float ll = (accum[3] > 0.0f) ? 0.0f : accum[2] * invN;
    out[0] = 1.0f * l1 + 1.0f * ln + 0.1f * ll;
}

// ======================= FALLBACK PATH (round-1 atomic scatter) =======================

__global__ void __launch_bounds__(256) face_normals_kernel(
    const float* __restrict__ Vr, const float* __restrict__ Vg,
    const int* __restrict__ faces,
    float* __restrict__ vn_rec, float* __restrict__ vn_gt, int F)
{
    int f = blockIdx.x * blockDim.x + threadIdx.x;
    if (f >= F) return;
    int i0 = faces[3 * f + 0], i1 = faces[3 * f + 1], i2 = faces[3 * f + 2];
    {
        float v0x = Vr[3 * i0], v0y = Vr[3 * i0 + 1], v0z = Vr[3 * i0 + 2];
        float v1x = Vr[3 * i1], v1y = Vr[3 * i1 + 1], v1z = Vr[3 * i1 + 2];
        float v2x = Vr[3 * i2], v2y = Vr[3 * i2 + 1], v2z = Vr[3 * i2 + 2];
        float ax = v1x - v0x, ay = v1y - v0y, az = v1z - v0z;
        float bx = v2x - v0x, by = v2y - v0y, bz = v2z - v0z;
        float nx = ay * bz - az * by, ny = az * bx - ax * bz, nz = ax * by - ay * bx;
        atomAddF(&vn_rec[3 * i0], nx); atomAddF(&vn_rec[3 * i0 + 1], ny); atomAddF(&vn_rec[3 * i0 + 2], nz);
        atomAddF(&vn_rec[3 * i1], nx); atomAddF(&vn_rec[3 * i1 + 1], ny); atomAddF(&vn_rec[3 * i1 + 2], nz);
        atomAddF(&vn_rec[3 * i2], nx); atomAddF(&vn_rec[3 * i2 + 1], ny); atomAddF(&vn_rec[3 * i2 + 2], nz);
    }
    {
        float v0x = Vg[3 * i0], v0y = Vg[3 * i0 + 1], v0z = Vg[3 * i0 + 2];
        float v1x = Vg[3 * i1], v1y = Vg[3 * i1 + 1], v1z = Vg[3 * i1 + 2];
        float v2x = Vg[3 * i2], v2y = Vg[3 * i2 + 1], v2z = Vg[3 * i2 + 2];
        float ax = v1x - v0x, ay = v1y - v0y, az = v1z - v0z;
        float bx = v2x - v0x, by = v2y - v0y, bz = v2z - v0z;
        float nx = ay * bz - az * by, ny = az * bx - ax * bz, nz = ax * by - ay * bx;
        atomAddF(&vn_gt[3 * i0], nx); atomAddF(&vn_gt[3 * i0 + 1], ny); atomAddF(&vn_gt[3 * i0 + 2], nz);
        atomAddF(&vn_gt[3 * i1], nx); atomAddF(&vn_gt[3 * i1 + 1], ny); atomAddF(&vn_gt[3 * i1 + 2], nz);
        atomAddF(&vn_gt[3 * i2], nx); atomAddF(&vn_gt[3 * i2 + 1], ny); atomAddF(&vn_gt[3 * i2 + 2], nz);
    }
}

__global__ void __launch_bounds__(256) spmm_kernel(
    const float* __restrict__ Vr, const float* __restrict__ Vg,
    const int* __restrict__ rows, const int* __restrict__ cols,
    const float* __restrict__ vals,
    float* __restrict__ dl_rec, float* __restrict__ dl_gt, int nnz)
{
    int i = blockIdx.x * blockDim.x + threadIdx.x;
    if (i >= nnz) return;
    int r = rows[i], c = cols[i];
    float v = vals[i];
    float rx = Vr[3 * c], ry = Vr[3 * c + 1], rz = Vr[3 * c + 2];
    float gx = Vg[3 * c], gy = Vg[3 * c + 1], gz = Vg[3 * c + 2];
    atomAddF(&dl_rec[3 * r], v * rx); atomAddF(&dl_rec[3 * r + 1], v * ry); atomAddF(&dl_rec[3 * r + 2], v * rz);
    atomAddF(&dl_gt[3 * r], v * gx);  atomAddF(&dl_gt[3 * r + 1], v * gy);  atomAddF(&dl_gt[3 * r + 2], v * gz);
}

__global__ void __launch_bounds__(256) reduce_kernel(
    const float* __restrict__ Vr, const float* __restrict__ Vg,
    const float* __restrict__ vn_rec, const float* __restrict__ vn_gt,
    const float* __restrict__ dl_rec, const float* __restrict__ dl_gt,
    float* __restrict__ accum, int N)
{
    int i = blockIdx.x * blockDim.x + threadIdx.x;
    float l1 = 0.0f, ln = 0.0f, ll = 0.0f, nonfin = 0.0f;
    if (i < N) {
        float rx = Vr[3 * i], ry = Vr[3 * i + 1], rz = Vr[3 * i + 2];
        float gx = Vg[3 * i], gy = Vg[3 * i + 1], gz = Vg[3 * i + 2];
        l1 = fabsf(rx - gx) + fabsf(ry - gy) + fabsf(rz - gz);
        float ax = vn_rec[3 * i], ay = vn_rec[3 * i + 1], az = vn_rec[3 * i + 2];
        float bx = vn_gt[3 * i],  by = vn_gt[3 * i + 1],  bz = vn_gt[3 * i + 2];
        float na = sqrtf(ax * ax + ay * ay + az * az);
        float nb = sqrtf(bx * bx + by * by + bz * bz);
        float ia = 1.0f / fmaxf(na, NORM_EPS_F);
        float ib = 1.0f / fmaxf(nb, NORM_EPS_F);
        ax *= ia; ay *= ia; az *= ia; bx *= ib; by *= ib; bz *= ib;
        float dot = ax * bx + ay * by + az * bz;
        float nna = sqrtf(ax * ax + ay * ay + az * az);
        float nnb = sqrtf(bx * bx + by * by + bz * bz);
        float cosn = dot / (fmaxf(nna, COS_EPS_F) * fmaxf(nnb, COS_EPS_F));
        if (isnan(cosn)) cosn = 1.0f;
        ln = 1.0f - cosn;
        float px = dl_rec[3 * i], py = dl_rec[3 * i + 1], pz = dl_rec[3 * i + 2];
        float qx = dl_gt[3 * i],  qy = dl_gt[3 * i + 1],  qz = dl_gt[3 * i + 2];
        bool fin = isfinite(px) && isfinite(py) && isfinite(pz) &&
                   isfinite(qx) && isfinite(qy) && isfinite(qz);
        nonfin = fin ? 0.0f : 1.0f;
        float dotl = px * qx + py * qy + pz * qz;
        float npn = sqrtf(px * px + py * py + pz * pz);
        float nqn = sqrtf(qx * qx + qy * qy + qz * qz);
        float cosl = dotl / (fmaxf(npn, COS_EPS_F) * fmaxf(nqn, COS_EPS_F));
        if (isnan(cosl)) cosl = 1.0f;
        ll = 1.0f - cosl;
    }
    for (int off = 32; off > 0; off >>= 1) {
        l1 += __shfl_down(l1, off, 64);
        ln += __shfl_down(ln, off, 64);
        ll += __shfl_down(ll, off, 64);
        nonfin += __shfl_down(nonfin, off, 64);
    }
    __shared__ float s[4][4];
    int wave = threadIdx.x >> 6, lane = threadIdx.x & 63;
    if (lane == 0) { s[wave][0] = l1; s[wave][1] = ln; s[wave][2] = ll; s[wave][3] = nonfin; }
    __syncthreads();
    if (threadIdx.x == 0) {
        float a = 0, b = 0, c = 0, d = 0;
        int nw = (blockDim.x + 63) >> 6;
        for (int w = 0; w < nw; ++w) { a += s[w][0]; b += s[w][1]; c += s[w][2]; d += s[w][3]; }
        atomAddF(&accum[0], a); atomAddF(&accum[1], b);
        atomAddF(&accum[2], c); atomAddF(&accum[3], d);
    }
}

// ======================= launch =======================

extern "C" void kernel_launch(void* const* d_in, const int* in_sizes, int n_in,
                              void* d_out, int out_size, void* d_ws, size_t ws_size,
                              hipStream_t stream)
{
    const float* Vr    = (const float*)d_in[0];
    const float* Vg    = (const float*)d_in[1];
    const int*   faces = (const int*)d_in[2];
    const int*   Lr    = (const int*)d_in[3];
    const int*   Lc    = (const int*)d_in[4];
    const float* Lv    = (const float*)d_in[5];

    const int N   = in_sizes[0] / 3;
    const int F   = in_sizes[2] / 3;
    const int NNZ = in_sizes[3];
    const int NB  = (N + BK - 1) / BK;

    int avgF = (3 * F) / NB + 1;
    int avgL = NNZ / NB + 1;
    int capF = avgF + ((avgF / 8) > 512 ? (avgF / 8) : 512);
    int capL = avgL + ((avgL / 8) > 512 ? (avgL / 8) : 512);

    // workspace layout (in 4-byte words)
    size_t o = 0;
    size_t accum_o = o; o += 4;
    size_t cntF_o  = o; o += NB;
    size_t cntL_o  = o; o += NB;
    o = (o + 3) & ~(size_t)3;
    size_t Vr4_o = o; o += (size_t)4 * N;
    size_t Vg4_o = o; o += (size_t)4 * N;
    size_t fnr_o = o; o += (size_t)4 * F;
    size_t fng_o = o; o += (size_t)4 * F;
    size_t recF_o = o; o += (size_t)NB * capF * 2;
    o = (o + 3) & ~(size_t)3;
    size_t recL_o = o; o += (size_t)NB * capL * 4;
    size_t need = o * 4;

    float* ws = (float*)d_ws;
    const int B = 256;

    if (NB <= 1024 && need <= ws_size) {
        // ---- fast bucketed path ----
        float*  accum = ws + accum_o;
        int*    cntF  = (int*)(ws + cntF_o);
        int*    cntL  = (int*)(ws + cntL_o);
        float4* Vr4   = (float4*)(ws + Vr4_o);
        float4* Vg4   = (float4*)(ws + Vg4_o);
        float4* fnr   = (float4*)(ws + fnr_o);
        float4* fng   = (float4*)(ws + fng_o);
        int2*   recF  = (int2*)(ws + recF_o);
        int4*   recL  = (int4*)(ws + recL_o);

        hipMemsetAsync(ws, 0, (4 + 2 * (size_t)NB) * 4, stream);  // accum + counters

        pack_verts_kernel<<<dim3((N + B - 1) / B), dim3(B), 0, stream>>>(Vr, Vg, Vr4, Vg4, N);
        face_normals2_kernel<<<dim3((F + B - 1) / B), dim3(B), 0, stream>>>(Vr4, Vg4, faces, fnr, fng, F);

        const int CHF = 4096, CHL = 8192;
        bucket_faces_kernel<<<dim3((F + CHF - 1) / CHF), dim3(B), 0, stream>>>(
            faces, cntF, recF, capF, F, NB, CHF);
        bucket_L_kernel<<<dim3((NNZ + CHL - 1) / CHL), dim3(B), 0, stream>>>(
            Lr, Lc, Lv, cntL, recL, capL, NNZ, NB, CHL);

        accum_loss_kernel<<<dim3(NB), dim3(B), 0, stream>>>(
            Vr4, Vg4, fnr, fng, cntF, recF, capF, cntL, recL, capL, accum, N);

        finalize_kernel<<<dim3(1), dim3(1), 0, stream>>>(accum, (float*)d_out, N);
    } else {
        // ---- fallback: round-1 atomic scatter path ----
        float* vn_rec = ws;
        float* vn_gt  = ws + (size_t)3 * N;
        float* dl_rec = ws + (size_t)6 * N;
        float* dl_gt  = ws + (size_t)9 * N;
        float* accum  = ws + (size_t)12 * N;
        hipMemsetAsync(d_ws, 0, ((size_t)12 * N + 4) * sizeof(float), stream);
        face_normals_kernel<<<dim3((F + B - 1) / B), dim3(B), 0, stream>>>(Vr, Vg, faces, vn_rec, vn_gt, F);
        spmm_kernel<<<dim3((NNZ + B - 1) / B), dim3(B), 0, stream>>>(Vr, Vg, Lr, Lc, Lv, dl_rec, dl_gt, NNZ);
        reduce_kernel<<<dim3((N + B - 1) / B), dim3(B), 0, stream>>>(Vr, Vg, vn_rec, vn_gt, dl_rec, dl_gt, accum, N);
        finalize_kernel<<<dim3(1), dim3(1), 0, stream>>>(accum, (float*)d_out, N);
    }
}

// Round 3
// 1101.760 us; speedup vs baseline: 4.0122x; 4.0122x over previous
//
#include <hip/hip_runtime.h>
#include <hip/hip_bf16.h>

#define NORM_EPS_F 1e-6f
#define COS_EPS_F  1e-8f
#define BK   1024      // vertices per bucket
#define BKSH 10

__device__ __forceinline__ void atomAddF(float* p, float v) {
    unsafeAtomicAdd(p, v);   // hardware global_atomic_add_f32
}

// Block-wide reduce of NV floats -> NV global atomics. Must be called by ALL
// threads of a 256-thread block (contains __syncthreads).
template<int NV>
__device__ __forceinline__ void blockReduceAtomicN(float (&v)[NV], float* dst) {
    #pragma unroll
    for (int off = 32; off > 0; off >>= 1) {
        #pragma unroll
        for (int k = 0; k < NV; ++k) v[k] += __shfl_down(v[k], off, 64);
    }
    __shared__ float red[4][NV];
    int wave = threadIdx.x >> 6, lane = threadIdx.x & 63;
    if (lane == 0) {
        #pragma unroll
        for (int k = 0; k < NV; ++k) red[wave][k] = v[k];
    }
    __syncthreads();
    if (threadIdx.x == 0) {
        float s[NV];
        #pragma unroll
        for (int k = 0; k < NV; ++k) s[k] = 0.f;
        for (int w = 0; w < 4; ++w)
            #pragma unroll
            for (int k = 0; k < NV; ++k) s[k] += red[w][k];
        #pragma unroll
        for (int k = 0; k < NV; ++k) atomAddF(&dst[k], s[k]);
    }
}

// ======================= FAST PATH =======================

// Pack V into 32B/vertex {rec.xyz,0, gt.xyz,0} (gathers then cost exactly one
// 64B line) and fold the L1 term in (saves a separate 24MB pass).
__global__ void __launch_bounds__(256) pack_l1_kernel(
    const float* __restrict__ Vr, const float* __restrict__ Vg,
    float4* __restrict__ Vp, float* __restrict__ accum, int N)
{
    int i = blockIdx.x * blockDim.x + threadIdx.x;
    float l1[1] = {0.f};
    if (i < N) {
        float rx = Vr[3 * i], ry = Vr[3 * i + 1], rz = Vr[3 * i + 2];
        float gx = Vg[3 * i], gy = Vg[3 * i + 1], gz = Vg[3 * i + 2];
        Vp[2 * i]     = make_float4(rx, ry, rz, 0.f);
        Vp[2 * i + 1] = make_float4(gx, gy, gz, 0.f);
        l1[0] = fabsf(rx - gx) + fabsf(ry - gy) + fabsf(rz - gz);
    }
    blockReduceAtomicN<1>(l1, &accum[0]);
}

// Face normals for both meshes -> packed {nr, ng} float4 pairs (tier A only).
__global__ void __launch_bounds__(256) fn_kernel(
    const float4* __restrict__ Vp, const int* __restrict__ faces,
    float4* __restrict__ FN, int F)
{
    int f = blockIdx.x * blockDim.x + threadIdx.x;
    if (f >= F) return;
    int i0 = faces[3 * f], i1 = faces[3 * f + 1], i2 = faces[3 * f + 2];
    float4 r0 = Vp[2 * i0], r1 = Vp[2 * i1], r2 = Vp[2 * i2];
    float4 g0 = Vp[2 * i0 + 1], g1 = Vp[2 * i1 + 1], g2 = Vp[2 * i2 + 1];
    {
        float ax = r1.x - r0.x, ay = r1.y - r0.y, az = r1.z - r0.z;
        float bx = r2.x - r0.x, by = r2.y - r0.y, bz = r2.z - r0.z;
        FN[2 * f] = make_float4(ay * bz - az * by, az * bx - ax * bz, ax * by - ay * bx, 0.f);
    }
    {
        float ax = g1.x - g0.x, ay = g1.y - g0.y, az = g1.z - g0.z;
        float bx = g2.x - g0.x, by = g2.y - g0.y, bz = g2.z - g0.z;
        FN[2 * f + 1] = make_float4(ay * bz - az * by, az * bx - ax * bz, ax * by - ay * bx, 0.f);
    }
}

// Bucket face incidences whose vertex falls in bucket range [b0, b0+bcnt).
// Record = (face<<10)|localVertex, 4B.
__global__ void __launch_bounds__(256) bucket_faces_kernel(
    const int* __restrict__ faces, int* __restrict__ cnt,
    unsigned* __restrict__ recF, int capF, int F, int b0, int bcnt, int chunk)
{
    __shared__ int hist[1024];
    int f0 = blockIdx.x * chunk;
    int f1 = min(f0 + chunk, F);
    for (int b = threadIdx.x; b < bcnt; b += blockDim.x) hist[b] = 0;
    __syncthreads();
    for (int f = f0 + threadIdx.x; f < f1; f += blockDim.x) {
        #pragma unroll
        for (int c = 0; c < 3; ++c) {
            unsigned bb = ((unsigned)faces[3 * f + c] >> BKSH) - (unsigned)b0;
            if (bb < (unsigned)bcnt) atomicAdd(&hist[bb], 1);
        }
    }
    __syncthreads();
    for (int b = threadIdx.x; b < bcnt; b += blockDim.x) {
        int h = hist[b];
        if (h) hist[b] = atomicAdd(&cnt[b], h);   // reserve [base, base+h)
    }
    __syncthreads();
    for (int f = f0 + threadIdx.x; f < f1; f += blockDim.x) {
        #pragma unroll
        for (int c = 0; c < 3; ++c) {
            int vtx = faces[3 * f + c];
            unsigned bb = ((unsigned)vtx >> BKSH) - (unsigned)b0;
            if (bb < (unsigned)bcnt) {
                int pos = atomicAdd(&hist[bb], 1);
                if (pos < capF)
                    recF[(size_t)bb * capF + pos] =
                        ((unsigned)f << BKSH) | (unsigned)(vtx & (BK - 1));
            }
        }
    }
}

// One block per bucket: accumulate vertex normals in LDS, then the normal-cos
// loss for this bucket's vertices. use_fn: read precomputed FN; else recompute.
__global__ void __launch_bounds__(256) accum_normals_kernel(
    const float4* __restrict__ Vp, const float4* __restrict__ FN,
    const int* __restrict__ faces,
    const int* __restrict__ cnt, const unsigned* __restrict__ recF, int capF,
    float* __restrict__ accum, int N, int b0, int use_fn)
{
    __shared__ float vnr[3 * BK];
    __shared__ float vng[3 * BK];
    int g = blockIdx.x;
    for (int i = threadIdx.x; i < 3 * BK; i += blockDim.x) { vnr[i] = 0.f; vng[i] = 0.f; }
    __syncthreads();

    int n = min(cnt[g], capF);
    for (int i = threadIdx.x; i < n; i += blockDim.x) {
        unsigned rec = recF[(size_t)g * capF + i];
        int lv = rec & (BK - 1);
        int f  = rec >> BKSH;
        float4 nr, ng;
        if (use_fn) {
            nr = FN[2 * f];
            ng = FN[2 * f + 1];
        } else {
            int i0 = faces[3 * f], i1 = faces[3 * f + 1], i2 = faces[3 * f + 2];
            float4 r0 = Vp[2 * i0], r1 = Vp[2 * i1], r2 = Vp[2 * i2];
            float4 g0 = Vp[2 * i0 + 1], g1 = Vp[2 * i1 + 1], g2 = Vp[2 * i2 + 1];
            float ax = r1.x - r0.x, ay = r1.y - r0.y, az = r1.z - r0.z;
            float bx = r2.x - r0.x, by = r2.y - r0.y, bz = r2.z - r0.z;
            nr = make_float4(ay * bz - az * by, az * bx - ax * bz, ax * by - ay * bx, 0.f);
            ax = g1.x - g0.x; ay = g1.y - g0.y; az = g1.z - g0.z;
            bx = g2.x - g0.x; by = g2.y - g0.y; bz = g2.z - g0.z;
            ng = make_float4(ay * bz - az * by, az * bx - ax * bz, ax * by - ay * bx, 0.f);
        }
        atomicAdd(&vnr[3 * lv + 0], nr.x);
        atomicAdd(&vnr[3 * lv + 1], nr.y);
        atomicAdd(&vnr[3 * lv + 2], nr.z);
        atomicAdd(&vng[3 * lv + 0], ng.x);
        atomicAdd(&vng[3 * lv + 1], ng.y);
        atomicAdd(&vng[3 * lv + 2], ng.z);
    }
    __syncthreads();

    float ln[1] = {0.f};
    for (int lv = threadIdx.x; lv < BK; lv += blockDim.x) {
        int gv = ((b0 + g) << BKSH) + lv;
        if (gv < N) {
            float ax = vnr[3 * lv], ay = vnr[3 * lv + 1], az = vnr[3 * lv + 2];
            float bx = vng[3 * lv], by = vng[3 * lv + 1], bz = vng[3 * lv + 2];
            float na = sqrtf(ax * ax + ay * ay + az * az);
            float nb = sqrtf(bx * bx + by * by + bz * bz);
            float ia = 1.0f / fmaxf(na, NORM_EPS_F);
            float ib = 1.0f / fmaxf(nb, NORM_EPS_F);
            ax *= ia; ay *= ia; az *= ia;
            bx *= ib; by *= ib; bz *= ib;
            float dot = ax * bx + ay * by + az * bz;
            float nna = sqrtf(ax * ax + ay * ay + az * az);
            float nnb = sqrtf(bx * bx + by * by + bz * bz);
            float cosn = dot / (fmaxf(nna, COS_EPS_F) * fmaxf(nnb, COS_EPS_F));
            if (isnan(cosn)) cosn = 1.0f;
            ln[0] += 1.0f - cosn;
        }
    }
    blockReduceAtomicN<1>(ln, &accum[1]);
}

// Bucket Laplacian triplets by row bucket. Record = {(col<<10)|lv, val}, 8B.
__global__ void __launch_bounds__(256) bucket_L_kernel(
    const int* __restrict__ rows, const int* __restrict__ cols,
    const float* __restrict__ vals, int* __restrict__ cnt,
    int2* __restrict__ recL, int capL, int nnz, int b0, int bcnt, int chunk)
{
    __shared__ int hist[1024];
    int i0 = blockIdx.x * chunk;
    int i1 = min(i0 + chunk, nnz);
    for (int b = threadIdx.x; b < bcnt; b += blockDim.x) hist[b] = 0;
    __syncthreads();
    for (int i = i0 + threadIdx.x; i < i1; i += blockDim.x) {
        unsigned bb = ((unsigned)rows[i] >> BKSH) - (unsigned)b0;
        if (bb < (unsigned)bcnt) atomicAdd(&hist[bb], 1);
    }
    __syncthreads();
    for (int b = threadIdx.x; b < bcnt; b += blockDim.x) {
        int h = hist[b];
        if (h) hist[b] = atomicAdd(&cnt[b], h);
    }
    __syncthreads();
    for (int i = i0 + threadIdx.x; i < i1; i += blockDim.x) {
        int r = rows[i];
        unsigned bb = ((unsigned)r >> BKSH) - (unsigned)b0;
        if (bb < (unsigned)bcnt) {
            int pos = atomicAdd(&hist[bb], 1);
            if (pos < capL)
                recL[(size_t)bb * capL + pos] = make_int2(
                    (int)(((unsigned)cols[i] << BKSH) | (unsigned)(r & (BK - 1))),
                    __float_as_int(vals[i]));
        }
    }
}

// One block per bucket: accumulate Laplacian deltas in LDS, then lap-cos loss.
__global__ void __launch_bounds__(256) accum_lap_kernel(
    const float4* __restrict__ Vp,
    const int* __restrict__ cnt, const int2* __restrict__ recL, int capL,
    float* __restrict__ accum, int N, int b0)
{
    __shared__ float dlr[3 * BK];
    __shared__ float dlg[3 * BK];
    int g = blockIdx.x;
    for (int i = threadIdx.x; i < 3 * BK; i += blockDim.x) { dlr[i] = 0.f; dlg[i] = 0.f; }
    __syncthreads();

    int n = min(cnt[g], capL);
    for (int i = threadIdx.x; i < n; i += blockDim.x) {
        int2 rc = recL[(size_t)g * capL + i];
        unsigned u = (unsigned)rc.x;
        int lv  = u & (BK - 1);
        int col = u >> BKSH;
        float v = __int_as_float(rc.y);
        float4 pr = Vp[2 * col];
        float4 pg = Vp[2 * col + 1];
        atomicAdd(&dlr[3 * lv + 0], v * pr.x);
        atomicAdd(&dlr[3 * lv + 1], v * pr.y);
        atomicAdd(&dlr[3 * lv + 2], v * pr.z);
        atomicAdd(&dlg[3 * lv + 0], v * pg.x);
        atomicAdd(&dlg[3 * lv + 1], v * pg.y);
        atomicAdd(&dlg[3 * lv + 2], v * pg.z);
    }
    __syncthreads();

    float vals2[2] = {0.f, 0.f};   // {lap loss, nonfinite count}
    for (int lv = threadIdx.x; lv < BK; lv += blockDim.x) {
        int gv = ((b0 + g) << BKSH) + lv;
        if (gv < N) {
            float px = dlr[3 * lv], py = dlr[3 * lv + 1], pz = dlr[3 * lv + 2];
            float qx = dlg[3 * lv], qy = dlg[3 * lv + 1], qz = dlg[3 * lv + 2];
            bool fin = isfinite(px) && isfinite(py) && isfinite(pz) &&
                       isfinite(qx) && isfinite(qy) && isfinite(qz);
            vals2[1] += fin ? 0.f : 1.f;
            float dotl = px * qx + py * qy + pz * qz;
            float npn = sqrtf(px * px + py * py + pz * pz);
            float nqn = sqrtf(qx * qx + qy * qy + qz * qz);
            float cosl = dotl / (fmaxf(npn, COS_EPS_F) * fmaxf(nqn, COS_EPS_F));
            if (isnan(cosl)) cosl = 1.0f;
            vals2[0] += 1.0f - cosl;
        }
    }
    blockReduceAtomicN<2>(vals2, &accum[2]);
}

__global__ void finalize_kernel(const float* __restrict__ accum,
                                float* __restrict__ out, int N)
{
    float invN = 1.0f / (float)N;
    float l1 = accum[0] * invN * (1.0f / 3.0f);
    float ln = accum[1] * invN;
    float ll = (accum[3] > 0.0f) ? 0.0f : accum[2] * invN;
    out[0] = 1.0f * l1 + 1.0f * ln + 0.1f * ll;
}

// ======================= FALLBACK PATH (round-1, known correct) =======================

__global__ void __launch_bounds__(256) face_normals_kernel(
    const float* __restrict__ Vr, const float* __restrict__ Vg,
    const int* __restrict__ faces,
    float* __restrict__ vn_rec, float* __restrict__ vn_gt, int F)
{
    int f = blockIdx.x * blockDim.x + threadIdx.x;
    if (f >= F) return;
    int i0 = faces[3 * f + 0], i1 = faces[3 * f + 1], i2 = faces[3 * f + 2];
    {
        float v0x = Vr[3 * i0], v0y = Vr[3 * i0 + 1], v0z = Vr[3 * i0 + 2];
        float v1x = Vr[3 * i1], v1y = Vr[3 * i1 + 1], v1z = Vr[3 * i1 + 2];
        float v2x = Vr[3 * i2], v2y = Vr[3 * i2 + 1], v2z = Vr[3 * i2 + 2];
        float ax = v1x - v0x, ay = v1y - v0y, az = v1z - v0z;
        float bx = v2x - v0x, by = v2y - v0y, bz = v2z - v0z;
        float nx = ay * bz - az * by, ny = az * bx - ax * bz, nz = ax * by - ay * bx;
        atomAddF(&vn_rec[3 * i0], nx); atomAddF(&vn_rec[3 * i0 + 1], ny); atomAddF(&vn_rec[3 * i0 + 2], nz);
        atomAddF(&vn_rec[3 * i1], nx); atomAddF(&vn_rec[3 * i1 + 1], ny); atomAddF(&vn_rec[3 * i1 + 2], nz);
        atomAddF(&vn_rec[3 * i2], nx); atomAddF(&vn_rec[3 * i2 + 1], ny); atomAddF(&vn_rec[3 * i2 + 2], nz);
    }
    {
        float v0x = Vg[3 * i0], v0y = Vg[3 * i0 + 1], v0z = Vg[3 * i0 + 2];
        float v1x = Vg[3 * i1], v1y = Vg[3 * i1 + 1], v1z = Vg[3 * i1 + 2];
        float v2x = Vg[3 * i2], v2y = Vg[3 * i2 + 1], v2z = Vg[3 * i2 + 2];
        float ax = v1x - v0x, ay = v1y - v0y, az = v1z - v0z;
        float bx = v2x - v0x, by = v2y - v0y, bz = v2z - v0z;
        float nx = ay * bz - az * by, ny = az * bx - ax * bz, nz = ax * by - ay * bx;
        atomAddF(&vn_gt[3 * i0], nx); atomAddF(&vn_gt[3 * i0 + 1], ny); atomAddF(&vn_gt[3 * i0 + 2], nz);
        atomAddF(&vn_gt[3 * i1], nx); atomAddF(&vn_gt[3 * i1 + 1], ny); atomAddF(&vn_gt[3 * i1 + 2], nz);
        atomAddF(&vn_gt[3 * i2], nx); atomAddF(&vn_gt[3 * i2 + 1], ny); atomAddF(&vn_gt[3 * i2 + 2], nz);
    }
}

__global__ void __launch_bounds__(256) spmm_kernel(
    const float* __restrict__ Vr, const float* __restrict__ Vg,
    const int* __restrict__ rows, const int* __restrict__ cols,
    const float* __restrict__ vals,
    float* __restrict__ dl_rec, float* __restrict__ dl_gt, int nnz)
{
    int i = blockIdx.x * blockDim.x + threadIdx.x;
    if (i >= nnz) return;
    int r = rows[i], c = cols[i];
    float v = vals[i];
    atomAddF(&dl_rec[3 * r], v * Vr[3 * c]);
    atomAddF(&dl_rec[3 * r + 1], v * Vr[3 * c + 1]);
    atomAddF(&dl_rec[3 * r + 2], v * Vr[3 * c + 2]);
    atomAddF(&dl_gt[3 * r], v * Vg[3 * c]);
    atomAddF(&dl_gt[3 * r + 1], v * Vg[3 * c + 1]);
    atomAddF(&dl_gt[3 * r + 2], v * Vg[3 * c + 2]);
}

__global__ void __launch_bounds__(256) reduce_kernel(
    const float* __restrict__ Vr, const float* __restrict__ Vg,
    const float* __restrict__ vn_rec, const float* __restrict__ vn_gt,
    const float* __restrict__ dl_rec, const float* __restrict__ dl_gt,
    float* __restrict__ accum, int N)
{
    int i = blockIdx.x * blockDim.x + threadIdx.x;
    float l1 = 0.0f, ln = 0.0f, ll = 0.0f, nonfin = 0.0f;
    if (i < N) {
        float rx = Vr[3 * i], ry = Vr[3 * i + 1], rz = Vr[3 * i + 2];
        float gx = Vg[3 * i], gy = Vg[3 * i + 1], gz = Vg[3 * i + 2];
        l1 = fabsf(rx - gx) + fabsf(ry - gy) + fabsf(rz - gz);
        float ax = vn_rec[3 * i], ay = vn_rec[3 * i + 1], az = vn_rec[3 * i + 2];
        float bx = vn_gt[3 * i],  by = vn_gt[3 * i + 1],  bz = vn_gt[3 * i + 2];
        float na = sqrtf(ax * ax + ay * ay + az * az);
        float nb = sqrtf(bx * bx + by * by + bz * bz);
        float ia = 1.0f / fmaxf(na, NORM_EPS_F);
        float ib = 1.0f / fmaxf(nb, NORM_EPS_F);
        ax *= ia; ay *= ia; az *= ia; bx *= ib; by *= ib; bz *= ib;
        float dot = ax * bx + ay * by + az * bz;
        float nna = sqrtf(ax * ax + ay * ay + az * az);
        float nnb = sqrtf(bx * bx + by * by + bz * bz);
        float cosn = dot / (fmaxf(nna, COS_EPS_F) * fmaxf(nnb, COS_EPS_F));
        if (isnan(cosn)) cosn = 1.0f;
        ln = 1.0f - cosn;
        float px = dl_rec[3 * i], py = dl_rec[3 * i + 1], pz = dl_rec[3 * i + 2];
        float qx = dl_gt[3 * i],  qy = dl_gt[3 * i + 1],  qz = dl_gt[3 * i + 2];
        bool fin = isfinite(px) && isfinite(py) && isfinite(pz) &&
                   isfinite(qx) && isfinite(qy) && isfinite(qz);
        nonfin = fin ? 0.0f : 1.0f;
        float dotl = px * qx + py * qy + pz * qz;
        float npn = sqrtf(px * px + py * py + pz * pz);
        float nqn = sqrtf(qx * qx + qy * qy + qz * qz);
        float cosl = dotl / (fmaxf(npn, COS_EPS_F) * fmaxf(nqn, COS_EPS_F));
        if (isnan(cosl)) cosl = 1.0f;
        ll = 1.0f - cosl;
    }
    float a[1] = {l1};  blockReduceAtomicN<1>(a, &accum[0]);
    float b[1] = {ln};  blockReduceAtomicN<1>(b, &accum[1]);
    float c2[2] = {ll, nonfin}; blockReduceAtomicN<2>(c2, &accum[2]);
}

// ======================= launch =======================

extern "C" void kernel_launch(void* const* d_in, const int* in_sizes, int n_in,
                              void* d_out, int out_size, void* d_ws, size_t ws_size,
                              hipStream_t stream)
{
    const float* Vr    = (const float*)d_in[0];
    const float* Vg    = (const float*)d_in[1];
    const int*   faces = (const int*)d_in[2];
    const int*   Lr    = (const int*)d_in[3];
    const int*   Lc    = (const int*)d_in[4];
    const float* Lv    = (const float*)d_in[5];

    const int N   = in_sizes[0] / 3;
    const int F   = in_sizes[2] / 3;
    const int NNZ = in_sizes[3];
    const int NB  = (N + BK - 1) >> BKSH;

    float* ws = (float*)d_ws;
    const int B = 256;

    // ---- adaptive plan (pure function of sizes -> identical every call) ----
    const long long baseW  = 1028;                 // accum(4) + cnt(1024)
    const long long vpackW = 8LL * N;              // packed V, 32B/vertex
    const long long fnW    = 8LL * F;              // packed face normals, 32B/face
    const long long totW   = (long long)(ws_size / 4);

    const int capF = 3 * F / (NB > 0 ? NB : 1) + 1 + 1024;
    const int capL = NNZ / (NB > 0 ? NB : 1) + 1 + 1024;

    long long availA = totW - baseW - vpackW - fnW;    // tier A record room
    long long availB = totW - baseW - vpackW;          // tier B record room
    bool tierA = availA >= (long long)capF * 64;
    long long availF = tierA ? availA : availB;

    int NBG_F = (int)(availF / capF);
    int NBG_L = (int)(availB / (2LL * capL));          // int2 = 2 words
    if (NBG_F > NB) NBG_F = NB;
    if (NBG_L > NB) NBG_L = NB;
    if (NBG_F > 1024) NBG_F = 1024;
    if (NBG_L > 1024) NBG_L = 1024;

    bool fast = (N <= (1 << 20)) && (F <= (1 << 22)) &&
                NBG_F >= 32 && NBG_L >= 32;

    if (fast) {
        float*    accum = ws;
        int*      cnt   = (int*)(ws + 4);
        float4*   Vp    = (float4*)(ws + baseW);
        float4*   FN    = (float4*)(ws + baseW + vpackW);
        unsigned* recF  = (unsigned*)(ws + baseW + vpackW + (tierA ? fnW : 0));
        int2*     recL  = (int2*)(ws + baseW + vpackW);   // reuses FN region

        hipMemsetAsync(accum, 0, 4 * sizeof(float), stream);

        pack_l1_kernel<<<dim3((N + B - 1) / B), dim3(B), 0, stream>>>(Vr, Vg, Vp, accum, N);
        if (tierA)
            fn_kernel<<<dim3((F + B - 1) / B), dim3(B), 0, stream>>>(Vp, faces, FN, F);

        const int CHF = 4096, CHL = 8192;
        int passF = (NB + NBG_F - 1) / NBG_F;
        for (int p = 0; p < passF; ++p) {
            int b0 = p * NBG_F;
            int bcnt = NB - b0 < NBG_F ? NB - b0 : NBG_F;
            hipMemsetAsync(cnt, 0, (size_t)bcnt * sizeof(int), stream);
            bucket_faces_kernel<<<dim3((F + CHF - 1) / CHF), dim3(B), 0, stream>>>(
                faces, cnt, recF, capF, F, b0, bcnt, CHF);
            accum_normals_kernel<<<dim3(bcnt), dim3(B), 0, stream>>>(
                Vp, FN, faces, cnt, recF, capF, accum, N, b0, tierA ? 1 : 0);
        }
        int passL = (NB + NBG_L - 1) / NBG_L;
        for (int p = 0; p < passL; ++p) {
            int b0 = p * NBG_L;
            int bcnt = NB - b0 < NBG_L ? NB - b0 : NBG_L;
            hipMemsetAsync(cnt, 0, (size_t)bcnt * sizeof(int), stream);
            bucket_L_kernel<<<dim3((NNZ + CHL - 1) / CHL), dim3(B), 0, stream>>>(
                Lr, Lc, Lv, cnt, recL, capL, NNZ, b0, bcnt, CHL);
            accum_lap_kernel<<<dim3(bcnt), dim3(B), 0, stream>>>(
                Vp, cnt, recL, capL, accum, N, b0);
        }
        finalize_kernel<<<dim3(1), dim3(1), 0, stream>>>(accum, (float*)d_out, N);
    } else {
        // ---- fallback: atomic scatter path ----
        float* vn_rec = ws;
        float* vn_gt  = ws + (size_t)3 * N;
        float* dl_rec = ws + (size_t)6 * N;
        float* dl_gt  = ws + (size_t)9 * N;
        float* accum  = ws + (size_t)12 * N;
        hipMemsetAsync(d_ws, 0, ((size_t)12 * N + 4) * sizeof(float), stream);
        face_normals_kernel<<<dim3((F + B - 1) / B), dim3(B), 0, stream>>>(Vr, Vg, faces, vn_rec, vn_gt, F);
        spmm_kernel<<<dim3((NNZ + B - 1) / B), dim3(B), 0, stream>>>(Vr, Vg, Lr, Lc, Lv, dl_rec, dl_gt, NNZ);
        reduce_kernel<<<dim3((N + B - 1) / B), dim3(B), 0, stream>>>(Vr, Vg, vn_rec, vn_gt, dl_rec, dl_gt, accum, N);
        finalize_kernel<<<dim3(1), dim3(1), 0, stream>>>(accum, (float*)d_out, N);
    }
}